// Round 4
// baseline (646.081 us; speedup 1.0000x reference)
//
#include <hip/hip_runtime.h>
#include <hip/hip_bf16.h>

#define UF 512
#define EF 256
#define NB 64
#define NU 1024
#define NEN 1024

typedef __attribute__((ext_vector_type(8))) short short8;   // 8 bf16 (4 VGPRs)
typedef __attribute__((ext_vector_type(4))) float floatx4;  // MFMA acc / ext-vector f32x4

typedef unsigned short ushort_t;

__device__ inline short2 cvt2(float a, float b) {
    __hip_bfloat162 h = __float22bfloat162_rn(make_float2(a, b));
    union { __hip_bfloat162 h; short2 s; } u;
    u.h = h;
    return u.s;
}

__device__ inline short8 cvt8v(floatx4 x, floatx4 y) {
    union { short8 v; short2 s[4]; } u;
    u.s[0] = cvt2(x[0], x[1]);
    u.s[1] = cvt2(x[2], x[3]);
    u.s[2] = cvt2(y[0], y[1]);
    u.s[3] = cvt2(y[2], y[3]);
    return u.v;
}

__device__ inline ushort_t f2bfbits(float f) {
    unsigned u = __float_as_uint(f);
    u += 0x7FFFu + ((u >> 16) & 1u);   // round-to-nearest-even
    return (ushort_t)(u >> 16);
}

// ---------------- K1: ||v||^2 ----------------
__global__ void knorm(const float* __restrict__ v, float* __restrict__ ws0) {
    int t = blockIdx.x * 256 + threadIdx.x;     // 65536 threads, float2 each
    float2 x = ((const float2*)v)[t];
    float s = x.x * x.x + x.y * x.y;
    #pragma unroll
    for (int m = 1; m < 64; m <<= 1) s += __shfl_xor(s, m);
    __shared__ float ls[4];
    int w = threadIdx.x >> 6;
    if ((threadIdx.x & 63) == 0) ls[w] = s;
    __syncthreads();
    if (threadIdx.x == 0) atomicAdd(ws0, ls[0] + ls[1] + ls[2] + ls[3]);
}

// ---------------- K2: W = g*v/||v|| -> bf16 (W only; E is read fp32 by kattn) ----------------
__global__ void kconvW(const float* __restrict__ v, const float* __restrict__ g,
                       const float* __restrict__ ws0, ushort_t* __restrict__ wsW) {
    int t = blockIdx.x * 256 + threadIdx.x;     // 32768 threads * 4 elems = 131072
    float s = g[0] * rsqrtf(ws0[0]);
    float4 x = ((const float4*)v)[t];
    short2 a = cvt2(x.x * s, x.y * s);
    short2 b = cvt2(x.z * s, x.w * s);
    ushort4 o;
    o.x = (ushort_t)a.x; o.y = (ushort_t)a.y; o.z = (ushort_t)b.x; o.w = (ushort_t)b.y;
    ((ushort4*)wsW)[t] = o;
}

// ---------------- K3: proj = relu(ufeat @ W^T + b) -> bf16 ----------------
// block: 32 m-rows x all 256 n-cols, grid 2048 (8 blocks/CU for TLP).
// acc[2][4] = 32 AGPRs; unroll-4 k-loop keeps ~16 loads in flight per wave.
// A loads are temporal: 4 waves/block read the same A lines (L1/L2 reuse).
__launch_bounds__(256, 2)
__global__ void kgemm1(const float* __restrict__ A, const ushort_t* __restrict__ W,
                       const float* __restrict__ bias, ushort_t* __restrict__ P) {
    const int tid = threadIdx.x;
    const int w = tid >> 6, L = tid & 63;
    const int rA = L & 15, q = L >> 4;
    const long mt = (long)blockIdx.x * 32;

    floatx4 acc[2][4];
    #pragma unroll
    for (int m = 0; m < 2; m++)
        #pragma unroll
        for (int n = 0; n < 4; n++) acc[m][n] = (floatx4){0.f, 0.f, 0.f, 0.f};

    const float* a0 = A + (mt + rA) * UF + q * 8;
    const float* a1 = A + (mt + 16 + rA) * UF + q * 8;
    const ushort_t* wp[4];
    #pragma unroll
    for (int n = 0; n < 4; n++) wp[n] = W + (long)(w * 64 + n * 16 + rA) * UF + q * 8;

    #pragma unroll 4
    for (int s = 0; s < 16; s++) {
        const int ko = s * 32;
        floatx4 x0 = *(const floatx4*)(a0 + ko);
        floatx4 y0 = *(const floatx4*)(a0 + ko + 4);
        floatx4 x1 = *(const floatx4*)(a1 + ko);
        floatx4 y1 = *(const floatx4*)(a1 + ko + 4);
        short8 af0 = cvt8v(x0, y0);
        short8 af1 = cvt8v(x1, y1);
        short8 bfr[4];
        #pragma unroll
        for (int n = 0; n < 4; n++) bfr[n] = *(const short8*)(wp[n] + ko);
        #pragma unroll
        for (int n = 0; n < 4; n++) {
            acc[0][n] = __builtin_amdgcn_mfma_f32_16x16x32_bf16(af0, bfr[n], acc[0][n], 0, 0, 0);
            acc[1][n] = __builtin_amdgcn_mfma_f32_16x16x32_bf16(af1, bfr[n], acc[1][n], 0, 0, 0);
        }
    }

    #pragma unroll
    for (int n = 0; n < 4; n++) {
        const int col = w * 64 + n * 16 + rA;
        const float bv = bias[col];
        #pragma unroll
        for (int m = 0; m < 2; m++) {
            #pragma unroll
            for (int i = 0; i < 4; i++) {
                float val = acc[m][n][i] + bv;
                val = fmaxf(val, 0.f);
                const long row = mt + m * 16 + q * 4 + i;
                P[row * EF + col] = f2bfbits(val);
            }
        }
    }
}

// ---------------- K4: logits -> (no-max) softmax -> prob ----------------
// block: one (b, ut32) pair; 32 u-rows x all 1024 n.
// Wave w owns INTERLEAVED 16-col steps: col0 = ns*64 + w*16 (balanced skip).
// E is read fp32 DIRECTLY from the input (no bf16 staging pass) and converted
// in-register at frag build -- identical RNE rounding, bit-identical numerics.
// b-major block order: E working set ~1MB/b, L2-resident, 32x reuse per b.
__launch_bounds__(256, 2)
__global__ void kattn(const ushort_t* __restrict__ P, const float* __restrict__ E,
                      const int* __restrict__ nen, float* __restrict__ out) {
    const int tid = threadIdx.x;
    const int w = tid >> 6, L = tid & 63;
    const int rA = L & 15, q = L >> 4;
    const int bid = blockIdx.x;
    const int b = bid >> 5;              // b-major
    const int ut = bid & 31;             // 0..31, 32 u-rows each
    const int ne = nen[b];

    // Preload A-frags (proj tile 32x256) once; reused across all active n-steps.
    const ushort_t* prow = P + (long)(b * NU + ut * 32 + rA) * EF + q * 8;
    short8 af[2][8];
    #pragma unroll
    for (int t = 0; t < 2; t++)
        #pragma unroll
        for (int s = 0; s < 8; s++)
            af[t][s] = *(const short8*)(prow + t * 16 * EF + s * 32);

    floatx4 acc[2][16];
    #pragma unroll
    for (int t = 0; t < 2; t++)
        #pragma unroll
        for (int ns = 0; ns < 16; ns++) acc[t][ns] = (floatx4){0.f, 0.f, 0.f, 0.f};
    float psum[2][4];
    #pragma unroll
    for (int t = 0; t < 2; t++)
        #pragma unroll
        for (int i = 0; i < 4; i++) psum[t][i] = 0.f;

    // E rows for this wave's steps: row = ns*64 + w*16 + rA (fp32, stride EF)
    const float* erow = E + (long)(b * NEN + w * 16 + rA) * EF + q * 8;

    #pragma unroll
    for (int ns = 0; ns < 16; ns++) {
        const int col0 = ns * 64 + w * 16;
        if (col0 < ne) {                 // wave-uniform skip, balanced across waves
            const float* ep = erow + (long)ns * 64 * EF;
            floatx4 c0 = (floatx4){0.f, 0.f, 0.f, 0.f};
            floatx4 c1 = (floatx4){0.f, 0.f, 0.f, 0.f};
            #pragma unroll
            for (int h = 0; h < 2; h++) {
                short8 bf[4];
                #pragma unroll
                for (int s = 0; s < 4; s++) {
                    const float* pe = ep + (h * 4 + s) * 32;
                    floatx4 ex = *(const floatx4*)(pe);
                    floatx4 ey = *(const floatx4*)(pe + 4);
                    bf[s] = cvt8v(ex, ey);
                }
                #pragma unroll
                for (int s = 0; s < 4; s++) {
                    c0 = __builtin_amdgcn_mfma_f32_16x16x32_bf16(af[0][h * 4 + s], bf[s], c0, 0, 0, 0);
                    c1 = __builtin_amdgcn_mfma_f32_16x16x32_bf16(af[1][h * 4 + s], bf[s], c1, 0, 0, 0);
                }
            }
            const int col = col0 + rA;
            const bool on = col < ne;    // boundary lanes masked off
            #pragma unroll
            for (int i = 0; i < 4; i++) {
                float e0 = on ? __expf(c0[i] * 0.0625f) : 0.f;
                float e1 = on ? __expf(c1[i] * 0.0625f) : 0.f;
                c0[i] = e0; c1[i] = e1;
                psum[0][i] += e0; psum[1][i] += e1;
            }
            acc[0][ns] = c0;
            acc[1][ns] = c1;
        }
    }

    // Row sums: reduce over the 16 lanes sharing q (cols), then across waves via LDS.
    #pragma unroll
    for (int t = 0; t < 2; t++)
        #pragma unroll
        for (int i = 0; i < 4; i++) {
            float s = psum[t][i];
            s += __shfl_xor(s, 1);
            s += __shfl_xor(s, 2);
            s += __shfl_xor(s, 4);
            s += __shfl_xor(s, 8);
            psum[t][i] = s;
        }
    __shared__ float lsum[4][32];
    if (rA == 0) {
        #pragma unroll
        for (int t = 0; t < 2; t++)
            #pragma unroll
            for (int i = 0; i < 4; i++)
                lsum[w][t * 16 + q * 4 + i] = psum[t][i];
    }
    __syncthreads();

    float inv[2][4];
    #pragma unroll
    for (int t = 0; t < 2; t++)
        #pragma unroll
        for (int i = 0; i < 4; i++) {
            const int r = t * 16 + q * 4 + i;
            const float tot = lsum[0][r] + lsum[1][r] + lsum[2][r] + lsum[3][r];
            inv[t][i] = (ne > 0) ? (1.f / tot) : 0.f;
        }

    const float uni = 1.f / 1024.f;
    // out is never re-read: nontemporal stores keep the 268MB stream out of L2.
    float* orow = out + ((long)(b * NU + ut * 32)) * (long)NEN + w * 16;
    #pragma unroll
    for (int ns = 0; ns < 16; ns++) {
        #pragma unroll
        for (int t = 0; t < 2; t++) {
            #pragma unroll
            for (int i = 0; i < 4; i++) {
                const int u = t * 16 + q * 4 + i;
                const float val = (ne == 0) ? uni : acc[t][ns][i] * inv[t][i];
                __builtin_nontemporal_store(val, &orow[(long)u * NEN + ns * 64 + rA]);
            }
        }
    }
}

extern "C" void kernel_launch(void* const* d_in, const int* in_sizes, int n_in,
                              void* d_out, int out_size, void* d_ws, size_t ws_size,
                              hipStream_t stream) {
    (void)in_sizes; (void)n_in; (void)out_size; (void)ws_size;
    const float* ufeat = (const float*)d_in[0];
    const float* efeat = (const float*)d_in[1];
    const int*   nen   = (const int*)d_in[2];
    const float* v     = (const float*)d_in[3];
    const float* g     = (const float*)d_in[4];
    const float* bias  = (const float*)d_in[5];
    float* out = (float*)d_out;

    float*    ws0 = (float*)d_ws;
    ushort_t* wsW = (ushort_t*)((char*)d_ws + 1024);        // 256 KB
    ushort_t* wsP = (ushort_t*)((char*)d_ws + (1u << 20));  // 32 MB

    hipMemsetAsync(d_ws, 0, 256, stream);
    knorm<<<256, 256, 0, stream>>>(v, ws0);
    kconvW<<<128, 256, 0, stream>>>(v, g, ws0, wsW);
    kgemm1<<<2048, 256, 0, stream>>>(ufeat, wsW, bias, wsP);
    kattn<<<2048, 256, 0, stream>>>(wsP, efeat, nen, out);
}

// Round 5
// 575.052 us; speedup vs baseline: 1.1235x; 1.1235x over previous
//
#include <hip/hip_runtime.h>
#include <hip/hip_bf16.h>

#define UF 512
#define EF 256
#define NB 64
#define NU 1024
#define NEN 1024

typedef __attribute__((ext_vector_type(8))) short short8;   // 8 bf16 (4 VGPRs)
typedef __attribute__((ext_vector_type(4))) float floatx4;  // MFMA acc / ext-vector f32x4

typedef unsigned short ushort_t;

__device__ inline short2 cvt2(float a, float b) {
    __hip_bfloat162 h = __float22bfloat162_rn(make_float2(a, b));
    union { __hip_bfloat162 h; short2 s; } u;
    u.h = h;
    return u.s;
}

__device__ inline short8 cvt8v(floatx4 x, floatx4 y) {
    union { short8 v; short2 s[4]; } u;
    u.s[0] = cvt2(x[0], x[1]);
    u.s[1] = cvt2(x[2], x[3]);
    u.s[2] = cvt2(y[0], y[1]);
    u.s[3] = cvt2(y[2], y[3]);
    return u.v;
}

__device__ inline ushort_t f2bfbits(float f) {
    unsigned u = __float_as_uint(f);
    u += 0x7FFFu + ((u >> 16) & 1u);   // round-to-nearest-even
    return (ushort_t)(u >> 16);
}

// ---------------- K1: ||v||^2 ----------------
__global__ void knorm(const float* __restrict__ v, float* __restrict__ ws0) {
    int t = blockIdx.x * 256 + threadIdx.x;     // 65536 threads, float2 each
    float2 x = ((const float2*)v)[t];
    float s = x.x * x.x + x.y * x.y;
    #pragma unroll
    for (int m = 1; m < 64; m <<= 1) s += __shfl_xor(s, m);
    __shared__ float ls[4];
    int w = threadIdx.x >> 6;
    if ((threadIdx.x & 63) == 0) ls[w] = s;
    __syncthreads();
    if (threadIdx.x == 0) atomicAdd(ws0, ls[0] + ls[1] + ls[2] + ls[3]);
}

// ---------------- K2: W=g*v/||v|| -> bf16 ; efeat -> bf16 (skip masked rows) ----------------
__global__ void kconv(const float* __restrict__ v, const float* __restrict__ g,
                      const float* __restrict__ ef, const float* __restrict__ ws0,
                      const int* __restrict__ nen,
                      ushort_t* __restrict__ wsW, ushort_t* __restrict__ wsE) {
    int bid = blockIdx.x;
    if (bid < 128) {
        int t = bid * 256 + threadIdx.x;        // 32768 threads * 4 elems = 131072
        float s = g[0] * rsqrtf(ws0[0]);
        float4 x = ((const float4*)v)[t];
        short2 a = cvt2(x.x * s, x.y * s);
        short2 b = cvt2(x.z * s, x.w * s);
        ushort4 o;
        o.x = (ushort_t)a.x; o.y = (ushort_t)a.y; o.z = (ushort_t)b.x; o.w = (ushort_t)b.y;
        ((ushort4*)wsW)[t] = o;
    } else {
        long t = (long)(bid - 128) * 256 + threadIdx.x;  // float4 index into efeat
        int row = (int)(t >> 6);                 // 64 float4 per 256-col row
        int n = row & (NEN - 1);
        int b = row >> 10;
        if (n < nen[b]) {                        // rows >= ne are never read by kattn
            float4 x = ((const float4*)ef)[t];
            short2 a = cvt2(x.x, x.y);
            short2 c = cvt2(x.z, x.w);
            ushort4 o;
            o.x = (ushort_t)a.x; o.y = (ushort_t)a.y; o.z = (ushort_t)c.x; o.w = (ushort_t)c.y;
            ((ushort4*)wsE)[t] = o;
        }
    }
}

// ---------------- K3: proj = relu(ufeat @ W^T + b) -> bf16 ----------------
// 4 waves/block, each wave owns an INDEPENDENT 32-row x 128-col output tile
// (no shared A rows, no barriers). acc[2][8] = 64 VGPRs, 16 independent
// MFMAs/k-step. A (the HBM stream) is manually prefetched one k-step ahead so
// its ~900cy latency hides under the MFMA+W-load block; W is L2-resident.
__launch_bounds__(256, 2)
__global__ void kgemm1(const float* __restrict__ A, const ushort_t* __restrict__ W,
                       const float* __restrict__ bias, ushort_t* __restrict__ P) {
    const int tid = threadIdx.x;
    const int wv = tid >> 6, L = tid & 63;
    const int rA = L & 15, q = L >> 4;
    const int mh = wv >> 1;                      // which 32-row half of the block
    const int nh = wv & 1;                       // which 128-col half
    const long m0 = (long)blockIdx.x * 64 + mh * 32;

    floatx4 acc[2][8];
    #pragma unroll
    for (int m = 0; m < 2; m++)
        #pragma unroll
        for (int n = 0; n < 8; n++) acc[m][n] = (floatx4){0.f, 0.f, 0.f, 0.f};

    const float* a0 = A + (m0 + rA) * UF + q * 8;
    const float* a1 = A + (m0 + 16 + rA) * UF + q * 8;
    const ushort_t* wb = W + (long)(nh * 128 + rA) * UF + q * 8;

    // prime the A pipeline (step 0)
    floatx4 x0 = *(const floatx4*)(a0);
    floatx4 y0 = *(const floatx4*)(a0 + 4);
    floatx4 x1 = *(const floatx4*)(a1);
    floatx4 y1 = *(const floatx4*)(a1 + 4);

    #pragma unroll 2
    for (int s = 0; s < 16; s++) {
        const int ko = s * 32;
        short8 wf[8];
        #pragma unroll
        for (int n = 0; n < 8; n++) wf[n] = *(const short8*)(wb + (long)n * 16 * UF + ko);
        short8 af0 = cvt8v(x0, y0);
        short8 af1 = cvt8v(x1, y1);
        if (s < 15) {                            // prefetch next step's A (HBM)
            x0 = *(const floatx4*)(a0 + ko + 32);
            y0 = *(const floatx4*)(a0 + ko + 36);
            x1 = *(const floatx4*)(a1 + ko + 32);
            y1 = *(const floatx4*)(a1 + ko + 36);
        }
        #pragma unroll
        for (int n = 0; n < 8; n++) {
            acc[0][n] = __builtin_amdgcn_mfma_f32_16x16x32_bf16(af0, wf[n], acc[0][n], 0, 0, 0);
            acc[1][n] = __builtin_amdgcn_mfma_f32_16x16x32_bf16(af1, wf[n], acc[1][n], 0, 0, 0);
        }
    }

    #pragma unroll
    for (int n = 0; n < 8; n++) {
        const int col = nh * 128 + n * 16 + rA;
        const float bv = bias[col];
        #pragma unroll
        for (int m = 0; m < 2; m++) {
            #pragma unroll
            for (int i = 0; i < 4; i++) {
                float val = acc[m][n][i] + bv;
                val = fmaxf(val, 0.f);
                const long row = m0 + m * 16 + q * 4 + i;
                P[row * EF + col] = f2bfbits(val);
            }
        }
    }
}

// ---------------- K4: logits -> (no-max) softmax -> prob ----------------
// (round-3 version, best measured) block: one (b, ut32) pair; 32 u-rows x 1024 n.
// Wave w owns INTERLEAVED 16-col steps: col0 = ns*64 + w*16 (balanced skip).
// Two independent MFMA chains for ILP; b-major order for L2; nontemporal out.
__launch_bounds__(256, 2)
__global__ void kattn(const ushort_t* __restrict__ P, const ushort_t* __restrict__ E,
                      const int* __restrict__ nen, float* __restrict__ out) {
    const int tid = threadIdx.x;
    const int w = tid >> 6, L = tid & 63;
    const int rA = L & 15, q = L >> 4;
    const int bid = blockIdx.x;
    const int b = bid >> 5;              // b-major
    const int ut = bid & 31;             // 0..31, 32 u-rows each
    const int ne = nen[b];

    // Preload A-frags (proj tile 32x256) once; reused across all active n-steps.
    const ushort_t* prow = P + (long)(b * NU + ut * 32 + rA) * EF + q * 8;
    short8 af[2][8];
    #pragma unroll
    for (int t = 0; t < 2; t++)
        #pragma unroll
        for (int s = 0; s < 8; s++)
            af[t][s] = *(const short8*)(prow + t * 16 * EF + s * 32);

    floatx4 acc[2][16];
    #pragma unroll
    for (int t = 0; t < 2; t++)
        #pragma unroll
        for (int ns = 0; ns < 16; ns++) acc[t][ns] = (floatx4){0.f, 0.f, 0.f, 0.f};
    float psum[2][4];
    #pragma unroll
    for (int t = 0; t < 2; t++)
        #pragma unroll
        for (int i = 0; i < 4; i++) psum[t][i] = 0.f;

    // E rows for this wave's steps: row = ns*64 + w*16 + rA
    const ushort_t* erow = E + (long)(b * NEN + w * 16 + rA) * EF + q * 8;

    #pragma unroll
    for (int ns = 0; ns < 16; ns++) {
        const int col0 = ns * 64 + w * 16;
        if (col0 < ne) {                 // wave-uniform skip, balanced across waves
            const ushort_t* ep = erow + (long)ns * 64 * EF;
            floatx4 c0 = (floatx4){0.f, 0.f, 0.f, 0.f};
            floatx4 c1 = (floatx4){0.f, 0.f, 0.f, 0.f};
            #pragma unroll
            for (int h = 0; h < 2; h++) {
                short8 bf[4];
                #pragma unroll
                for (int s = 0; s < 4; s++) bf[s] = *(const short8*)(ep + (h * 4 + s) * 32);
                #pragma unroll
                for (int s = 0; s < 4; s++) {
                    c0 = __builtin_amdgcn_mfma_f32_16x16x32_bf16(af[0][h * 4 + s], bf[s], c0, 0, 0, 0);
                    c1 = __builtin_amdgcn_mfma_f32_16x16x32_bf16(af[1][h * 4 + s], bf[s], c1, 0, 0, 0);
                }
            }
            const int col = col0 + rA;
            const bool on = col < ne;    // boundary lanes: garbage E rows masked off
            #pragma unroll
            for (int i = 0; i < 4; i++) {
                float e0 = on ? __expf(c0[i] * 0.0625f) : 0.f;
                float e1 = on ? __expf(c1[i] * 0.0625f) : 0.f;
                c0[i] = e0; c1[i] = e1;
                psum[0][i] += e0; psum[1][i] += e1;
            }
            acc[0][ns] = c0;
            acc[1][ns] = c1;
        }
    }

    // Row sums: reduce over the 16 lanes sharing q (cols), then across waves via LDS.
    #pragma unroll
    for (int t = 0; t < 2; t++)
        #pragma unroll
        for (int i = 0; i < 4; i++) {
            float s = psum[t][i];
            s += __shfl_xor(s, 1);
            s += __shfl_xor(s, 2);
            s += __shfl_xor(s, 4);
            s += __shfl_xor(s, 8);
            psum[t][i] = s;
        }
    __shared__ float lsum[4][32];
    if (rA == 0) {
        #pragma unroll
        for (int t = 0; t < 2; t++)
            #pragma unroll
            for (int i = 0; i < 4; i++)
                lsum[w][t * 16 + q * 4 + i] = psum[t][i];
    }
    __syncthreads();

    float inv[2][4];
    #pragma unroll
    for (int t = 0; t < 2; t++)
        #pragma unroll
        for (int i = 0; i < 4; i++) {
            const int r = t * 16 + q * 4 + i;
            const float tot = lsum[0][r] + lsum[1][r] + lsum[2][r] + lsum[3][r];
            inv[t][i] = (ne > 0) ? (1.f / tot) : 0.f;
        }

    const float uni = 1.f / 1024.f;
    // out is never re-read: nontemporal stores keep the 268MB stream out of L2.
    float* orow = out + ((long)(b * NU + ut * 32)) * (long)NEN + w * 16;
    #pragma unroll
    for (int ns = 0; ns < 16; ns++) {
        #pragma unroll
        for (int t = 0; t < 2; t++) {
            #pragma unroll
            for (int i = 0; i < 4; i++) {
                const int u = t * 16 + q * 4 + i;
                const float val = (ne == 0) ? uni : acc[t][ns][i] * inv[t][i];
                __builtin_nontemporal_store(val, &orow[(long)u * NEN + ns * 64 + rA]);
            }
        }
    }
}

extern "C" void kernel_launch(void* const* d_in, const int* in_sizes, int n_in,
                              void* d_out, int out_size, void* d_ws, size_t ws_size,
                              hipStream_t stream) {
    (void)in_sizes; (void)n_in; (void)out_size; (void)ws_size;
    const float* ufeat = (const float*)d_in[0];
    const float* efeat = (const float*)d_in[1];
    const int*   nen   = (const int*)d_in[2];
    const float* v     = (const float*)d_in[3];
    const float* g     = (const float*)d_in[4];
    const float* bias  = (const float*)d_in[5];
    float* out = (float*)d_out;

    float*    ws0 = (float*)d_ws;
    ushort_t* wsW = (ushort_t*)((char*)d_ws + 1024);                       // 256 KB
    ushort_t* wsE = (ushort_t*)((char*)d_ws + (1u << 20));                 // 32 MB
    ushort_t* wsP = (ushort_t*)((char*)d_ws + (1u << 20) + (32u << 20));   // 32 MB

    hipMemsetAsync(d_ws, 0, 256, stream);
    knorm<<<256, 256, 0, stream>>>(v, ws0);
    kconv<<<16512, 256, 0, stream>>>(v, g, efeat, ws0, nen, wsW, wsE);
    kgemm1<<<1024, 256, 0, stream>>>(ufeat, wsW, bias, wsP);
    kattn<<<2048, 256, 0, stream>>>(wsP, wsE, nen, out);
}

// Round 6
// 569.220 us; speedup vs baseline: 1.1350x; 1.0102x over previous
//
#include <hip/hip_runtime.h>
#include <hip/hip_bf16.h>

#define UF 512
#define EF 256
#define NB 64
#define NU 1024
#define NEN 1024

typedef __attribute__((ext_vector_type(8))) short short8;   // 8 bf16 (4 VGPRs)
typedef __attribute__((ext_vector_type(4))) float floatx4;  // MFMA acc / ext-vector f32x4

typedef unsigned short ushort_t;

__device__ inline short2 cvt2(float a, float b) {
    __hip_bfloat162 h = __float22bfloat162_rn(make_float2(a, b));
    union { __hip_bfloat162 h; short2 s; } u;
    u.h = h;
    return u.s;
}

__device__ inline short8 cvt8v(floatx4 x, floatx4 y) {
    union { short8 v; short2 s[4]; } u;
    u.s[0] = cvt2(x[0], x[1]);
    u.s[1] = cvt2(x[2], x[3]);
    u.s[2] = cvt2(y[0], y[1]);
    u.s[3] = cvt2(y[2], y[3]);
    return u.v;
}

__device__ inline ushort_t f2bfbits(float f) {
    unsigned u = __float_as_uint(f);
    u += 0x7FFFu + ((u >> 16) & 1u);   // round-to-nearest-even
    return (ushort_t)(u >> 16);
}

// ---------------- K1: ||v||^2 ----------------
__global__ void knorm(const float* __restrict__ v, float* __restrict__ ws0) {
    int t = blockIdx.x * 256 + threadIdx.x;     // 65536 threads, float2 each
    float2 x = ((const float2*)v)[t];
    float s = x.x * x.x + x.y * x.y;
    #pragma unroll
    for (int m = 1; m < 64; m <<= 1) s += __shfl_xor(s, m);
    __shared__ float ls[4];
    int w = threadIdx.x >> 6;
    if ((threadIdx.x & 63) == 0) ls[w] = s;
    __syncthreads();
    if (threadIdx.x == 0) atomicAdd(ws0, ls[0] + ls[1] + ls[2] + ls[3]);
}

// ---------------- K2: W=g*v/||v|| -> bf16 ; efeat -> bf16 (skip masked rows) ----------------
__global__ void kconv(const float* __restrict__ v, const float* __restrict__ g,
                      const float* __restrict__ ef, const float* __restrict__ ws0,
                      const int* __restrict__ nen,
                      ushort_t* __restrict__ wsW, ushort_t* __restrict__ wsE) {
    int bid = blockIdx.x;
    if (bid < 128) {
        int t = bid * 256 + threadIdx.x;        // 32768 threads * 4 elems = 131072
        float s = g[0] * rsqrtf(ws0[0]);
        float4 x = ((const float4*)v)[t];
        short2 a = cvt2(x.x * s, x.y * s);
        short2 b = cvt2(x.z * s, x.w * s);
        ushort4 o;
        o.x = (ushort_t)a.x; o.y = (ushort_t)a.y; o.z = (ushort_t)b.x; o.w = (ushort_t)b.y;
        ((ushort4*)wsW)[t] = o;
    } else {
        long t = (long)(bid - 128) * 256 + threadIdx.x;  // float4 index into efeat
        int row = (int)(t >> 6);                 // 64 float4 per 256-col row
        int n = row & (NEN - 1);
        int b = row >> 10;
        if (n < nen[b]) {                        // rows >= ne are never read downstream
            // efeat is read exactly once: nontemporal, don't pollute L2.
            floatx4 x = __builtin_nontemporal_load((const floatx4*)ef + t);
            short2 a = cvt2(x[0], x[1]);
            short2 c = cvt2(x[2], x[3]);
            ushort4 o;
            o.x = (ushort_t)a.x; o.y = (ushort_t)a.y; o.z = (ushort_t)c.x; o.w = (ushort_t)c.y;
            ((ushort4*)wsE)[t] = o;
        }
    }
}

// ---------------- K3+K4 fused: proj GEMM -> LDS -> attention softmax ----------------
// Block = one (b, ut) pair; 2048 blocks, 4 waves.
// Phase 1: proj[32x256] = relu(ufeat[32x512] @ W^T + b): wave w owns cols
//   [w*64, w*64+64), acc[2][4], A prefetched one k-step ahead (round-5 scheme).
//   Epilogue deposits bf16 P-tile into 16KB LDS (f2bfbits — bit-identical to
//   the unfused P workspace).
// Phase 2: round-3 kattn, with A-frags read from LDS (one-time, conflict cost
//   negligible) instead of a 32MB HBM round-trip through wsP.
__launch_bounds__(256, 2)
__global__ void kfused(const float* __restrict__ A, const ushort_t* __restrict__ W,
                       const float* __restrict__ bias, const ushort_t* __restrict__ E,
                       const int* __restrict__ nen, float* __restrict__ out) {
    const int tid = threadIdx.x;
    const int w = tid >> 6, L = tid & 63;
    const int rA = L & 15, q = L >> 4;
    const int bid = blockIdx.x;
    const int b = bid >> 5;              // b-major: L2 locality on E
    const int ut = bid & 31;             // 0..31, 32 u-rows each
    const int ne = nen[b];

    __shared__ ushort_t Pl[32][256];     // 16 KB proj tile
    __shared__ float lsum[4][32];

    // ---- Phase 1: GEMM ----
    {
        const long m0 = (long)b * NU + (long)ut * 32;
        floatx4 acc[2][4];
        #pragma unroll
        for (int m = 0; m < 2; m++)
            #pragma unroll
            for (int n = 0; n < 4; n++) acc[m][n] = (floatx4){0.f, 0.f, 0.f, 0.f};

        const float* a0 = A + (m0 + rA) * UF + q * 8;
        const float* a1 = A + (m0 + 16 + rA) * UF + q * 8;
        const ushort_t* wp[4];
        #pragma unroll
        for (int n = 0; n < 4; n++) wp[n] = W + (long)(w * 64 + n * 16 + rA) * UF + q * 8;

        // prime the A pipeline (step 0)
        floatx4 x0 = *(const floatx4*)(a0);
        floatx4 y0 = *(const floatx4*)(a0 + 4);
        floatx4 x1 = *(const floatx4*)(a1);
        floatx4 y1 = *(const floatx4*)(a1 + 4);

        #pragma unroll 2
        for (int s = 0; s < 16; s++) {
            const int ko = s * 32;
            short8 wf[4];
            #pragma unroll
            for (int n = 0; n < 4; n++) wf[n] = *(const short8*)(wp[n] + ko);
            short8 af0 = cvt8v(x0, y0);
            short8 af1 = cvt8v(x1, y1);
            if (s < 15) {                        // prefetch next step's A (HBM)
                x0 = *(const floatx4*)(a0 + ko + 32);
                y0 = *(const floatx4*)(a0 + ko + 36);
                x1 = *(const floatx4*)(a1 + ko + 32);
                y1 = *(const floatx4*)(a1 + ko + 36);
            }
            #pragma unroll
            for (int n = 0; n < 4; n++) {
                acc[0][n] = __builtin_amdgcn_mfma_f32_16x16x32_bf16(af0, wf[n], acc[0][n], 0, 0, 0);
                acc[1][n] = __builtin_amdgcn_mfma_f32_16x16x32_bf16(af1, wf[n], acc[1][n], 0, 0, 0);
            }
        }

        #pragma unroll
        for (int n = 0; n < 4; n++) {
            const int col = w * 64 + n * 16 + rA;
            const float bv = bias[col];
            #pragma unroll
            for (int m = 0; m < 2; m++) {
                #pragma unroll
                for (int i = 0; i < 4; i++) {
                    float val = acc[m][n][i] + bv;
                    val = fmaxf(val, 0.f);
                    Pl[m * 16 + q * 4 + i][col] = f2bfbits(val);
                }
            }
        }
    }
    __syncthreads();

    // ---- Phase 2: attention ----
    // Preload A-frags from LDS (one-time); reused across all active n-steps.
    short8 af[2][8];
    #pragma unroll
    for (int t = 0; t < 2; t++)
        #pragma unroll
        for (int s = 0; s < 8; s++)
            af[t][s] = *(const short8*)&Pl[t * 16 + rA][s * 32 + q * 8];

    floatx4 acc[2][16];
    #pragma unroll
    for (int t = 0; t < 2; t++)
        #pragma unroll
        for (int ns = 0; ns < 16; ns++) acc[t][ns] = (floatx4){0.f, 0.f, 0.f, 0.f};
    float psum[2][4];
    #pragma unroll
    for (int t = 0; t < 2; t++)
        #pragma unroll
        for (int i = 0; i < 4; i++) psum[t][i] = 0.f;

    // E rows for this wave's INTERLEAVED steps: row = ns*64 + w*16 + rA
    const ushort_t* erow = E + (long)(b * NEN + w * 16 + rA) * EF + q * 8;

    #pragma unroll
    for (int ns = 0; ns < 16; ns++) {
        const int col0 = ns * 64 + w * 16;
        if (col0 < ne) {                 // wave-uniform skip, balanced across waves
            const ushort_t* ep = erow + (long)ns * 64 * EF;
            floatx4 c0 = (floatx4){0.f, 0.f, 0.f, 0.f};
            floatx4 c1 = (floatx4){0.f, 0.f, 0.f, 0.f};
            #pragma unroll
            for (int h = 0; h < 2; h++) {
                short8 bf[4];
                #pragma unroll
                for (int s = 0; s < 4; s++) bf[s] = *(const short8*)(ep + (h * 4 + s) * 32);
                #pragma unroll
                for (int s = 0; s < 4; s++) {
                    c0 = __builtin_amdgcn_mfma_f32_16x16x32_bf16(af[0][h * 4 + s], bf[s], c0, 0, 0, 0);
                    c1 = __builtin_amdgcn_mfma_f32_16x16x32_bf16(af[1][h * 4 + s], bf[s], c1, 0, 0, 0);
                }
            }
            const int col = col0 + rA;
            const bool on = col < ne;    // boundary lanes: garbage E rows masked off
            #pragma unroll
            for (int i = 0; i < 4; i++) {
                float e0 = on ? __expf(c0[i] * 0.0625f) : 0.f;
                float e1 = on ? __expf(c1[i] * 0.0625f) : 0.f;
                c0[i] = e0; c1[i] = e1;
                psum[0][i] += e0; psum[1][i] += e1;
            }
            acc[0][ns] = c0;
            acc[1][ns] = c1;
        }
    }

    // Row sums: reduce over the 16 lanes sharing q (cols), then across waves via LDS.
    #pragma unroll
    for (int t = 0; t < 2; t++)
        #pragma unroll
        for (int i = 0; i < 4; i++) {
            float s = psum[t][i];
            s += __shfl_xor(s, 1);
            s += __shfl_xor(s, 2);
            s += __shfl_xor(s, 4);
            s += __shfl_xor(s, 8);
            psum[t][i] = s;
        }
    if (rA == 0) {
        #pragma unroll
        for (int t = 0; t < 2; t++)
            #pragma unroll
            for (int i = 0; i < 4; i++)
                lsum[w][t * 16 + q * 4 + i] = psum[t][i];
    }
    __syncthreads();

    float inv[2][4];
    #pragma unroll
    for (int t = 0; t < 2; t++)
        #pragma unroll
        for (int i = 0; i < 4; i++) {
            const int r = t * 16 + q * 4 + i;
            const float tot = lsum[0][r] + lsum[1][r] + lsum[2][r] + lsum[3][r];
            inv[t][i] = (ne > 0) ? (1.f / tot) : 0.f;
        }

    const float uni = 1.f / 1024.f;
    // out is never re-read: nontemporal stores keep the 268MB stream out of L2.
    float* orow = out + ((long)(b * NU + ut * 32)) * (long)NEN + w * 16;
    #pragma unroll
    for (int ns = 0; ns < 16; ns++) {
        #pragma unroll
        for (int t = 0; t < 2; t++) {
            #pragma unroll
            for (int i = 0; i < 4; i++) {
                const int u = t * 16 + q * 4 + i;
                const float val = (ne == 0) ? uni : acc[t][ns][i] * inv[t][i];
                __builtin_nontemporal_store(val, &orow[(long)u * NEN + ns * 64 + rA]);
            }
        }
    }
}

extern "C" void kernel_launch(void* const* d_in, const int* in_sizes, int n_in,
                              void* d_out, int out_size, void* d_ws, size_t ws_size,
                              hipStream_t stream) {
    (void)in_sizes; (void)n_in; (void)out_size; (void)ws_size;
    const float* ufeat = (const float*)d_in[0];
    const float* efeat = (const float*)d_in[1];
    const int*   nen   = (const int*)d_in[2];
    const float* v     = (const float*)d_in[3];
    const float* g     = (const float*)d_in[4];
    const float* bias  = (const float*)d_in[5];
    float* out = (float*)d_out;

    float*    ws0 = (float*)d_ws;
    ushort_t* wsW = (ushort_t*)((char*)d_ws + 1024);        // 256 KB
    ushort_t* wsE = (ushort_t*)((char*)d_ws + (1u << 20));  // 32 MB

    hipMemsetAsync(d_ws, 0, 256, stream);
    knorm<<<256, 256, 0, stream>>>(v, ws0);
    kconv<<<16512, 256, 0, stream>>>(v, g, efeat, ws0, nen, wsW, wsE);
    kfused<<<2048, 256, 0, stream>>>(ufeat, wsW, bias, wsE, nen, out);
}

// Round 7
// 563.664 us; speedup vs baseline: 1.1462x; 1.0099x over previous
//
#include <hip/hip_runtime.h>
#include <hip/hip_bf16.h>

#define UF 512
#define EF 256
#define NB 64
#define NU 1024
#define NEN 1024

typedef __attribute__((ext_vector_type(8))) short short8;   // 8 bf16 (4 VGPRs)
typedef __attribute__((ext_vector_type(4))) float floatx4;  // MFMA acc / ext-vector f32x4
typedef __attribute__((ext_vector_type(2))) _Float16 half2v; // packed f16 pair (1 VGPR)

typedef unsigned short ushort_t;

__device__ inline short2 cvt2(float a, float b) {
    __hip_bfloat162 h = __float22bfloat162_rn(make_float2(a, b));
    union { __hip_bfloat162 h; short2 s; } u;
    u.h = h;
    return u.s;
}

__device__ inline short8 cvt8v(floatx4 x, floatx4 y) {
    union { short8 v; short2 s[4]; } u;
    u.s[0] = cvt2(x[0], x[1]);
    u.s[1] = cvt2(x[2], x[3]);
    u.s[2] = cvt2(y[0], y[1]);
    u.s[3] = cvt2(y[2], y[3]);
    return u.v;
}

__device__ inline ushort_t f2bfbits(float f) {
    unsigned u = __float_as_uint(f);
    u += 0x7FFFu + ((u >> 16) & 1u);   // round-to-nearest-even
    return (ushort_t)(u >> 16);
}

// ---------------- K1: ||v||^2 ----------------
__global__ void knorm(const float* __restrict__ v, float* __restrict__ ws0) {
    int t = blockIdx.x * 256 + threadIdx.x;     // 65536 threads, float2 each
    float2 x = ((const float2*)v)[t];
    float s = x.x * x.x + x.y * x.y;
    #pragma unroll
    for (int m = 1; m < 64; m <<= 1) s += __shfl_xor(s, m);
    __shared__ float ls[4];
    int w = threadIdx.x >> 6;
    if ((threadIdx.x & 63) == 0) ls[w] = s;
    __syncthreads();
    if (threadIdx.x == 0) atomicAdd(ws0, ls[0] + ls[1] + ls[2] + ls[3]);
}

// ---------------- K2: W=g*v/||v|| -> bf16 ; efeat -> bf16 (skip masked rows) ----------------
__global__ void kconv(const float* __restrict__ v, const float* __restrict__ g,
                      const float* __restrict__ ef, const float* __restrict__ ws0,
                      const int* __restrict__ nen,
                      ushort_t* __restrict__ wsW, ushort_t* __restrict__ wsE) {
    int bid = blockIdx.x;
    if (bid < 128) {
        int t = bid * 256 + threadIdx.x;        // 32768 threads * 4 elems = 131072
        float s = g[0] * rsqrtf(ws0[0]);
        float4 x = ((const float4*)v)[t];
        short2 a = cvt2(x.x * s, x.y * s);
        short2 b = cvt2(x.z * s, x.w * s);
        ushort4 o;
        o.x = (ushort_t)a.x; o.y = (ushort_t)a.y; o.z = (ushort_t)b.x; o.w = (ushort_t)b.y;
        ((ushort4*)wsW)[t] = o;
    } else {
        long t = (long)(bid - 128) * 256 + threadIdx.x;  // float4 index into efeat
        int row = (int)(t >> 6);                 // 64 float4 per 256-col row
        int n = row & (NEN - 1);
        int b = row >> 10;
        if (n < nen[b]) {                        // rows >= ne are never read downstream
            // efeat is read exactly once: nontemporal, don't pollute L2.
            floatx4 x = __builtin_nontemporal_load((const floatx4*)ef + t);
            short2 a = cvt2(x[0], x[1]);
            short2 c = cvt2(x[2], x[3]);
            ushort4 o;
            o.x = (ushort_t)a.x; o.y = (ushort_t)a.y; o.z = (ushort_t)c.x; o.w = (ushort_t)c.y;
            ((ushort4*)wsE)[t] = o;
        }
    }
}

// ---------------- K3+K4 fused: proj GEMM -> LDS -> attention softmax ----------------
// Block = one (b, ut) pair; 2048 blocks, 4 waves.
// Phase 1: proj[32x256] GEMM (A prefetched one k-step ahead), epilogue to LDS.
//   Pl padded to 264 cols (stride 132 words == 4 mod 32): af b128 reads drop
//   16-way -> 2-way (free), phase-1 writes ~8 -> ~4-way.
// Phase 2: attention with cross-step E prefetch: bf[2][8] double-buffer keyed
//   by ns&1 (compile-time under full unroll); step ns's body issues step
//   ns+1's 8 loads before its MFMAs. Activity is monotone in ns, so a garbage
//   prefetch on the last active step is never consumed (and stays in-bounds).
//   exp values stored as RTNE f16 pairs (64 VGPR, was 128 fp32) to pay for
//   the prefetch buffer; psum stays fp32 so the softmax denominator is exact.
__launch_bounds__(256, 2)
__global__ void kfused(const float* __restrict__ A, const ushort_t* __restrict__ W,
                       const float* __restrict__ bias, const ushort_t* __restrict__ E,
                       const int* __restrict__ nen, float* __restrict__ out) {
    const int tid = threadIdx.x;
    const int w = tid >> 6, L = tid & 63;
    const int rA = L & 15, q = L >> 4;
    const int bid = blockIdx.x;
    const int b = bid >> 5;              // b-major: L2 locality on E
    const int ut = bid & 31;             // 0..31, 32 u-rows each
    const int ne = nen[b];

    __shared__ ushort_t Pl[32][264];     // padded: 264*2B=528B row stride
    __shared__ float lsum[4][32];

    // ---- Phase 1: GEMM ----
    {
        const long m0 = (long)b * NU + (long)ut * 32;
        floatx4 acc[2][4];
        #pragma unroll
        for (int m = 0; m < 2; m++)
            #pragma unroll
            for (int n = 0; n < 4; n++) acc[m][n] = (floatx4){0.f, 0.f, 0.f, 0.f};

        const float* a0 = A + (m0 + rA) * UF + q * 8;
        const float* a1 = A + (m0 + 16 + rA) * UF + q * 8;
        const ushort_t* wp[4];
        #pragma unroll
        for (int n = 0; n < 4; n++) wp[n] = W + (long)(w * 64 + n * 16 + rA) * UF + q * 8;

        // prime the A pipeline (step 0)
        floatx4 x0 = *(const floatx4*)(a0);
        floatx4 y0 = *(const floatx4*)(a0 + 4);
        floatx4 x1 = *(const floatx4*)(a1);
        floatx4 y1 = *(const floatx4*)(a1 + 4);

        #pragma unroll 2
        for (int s = 0; s < 16; s++) {
            const int ko = s * 32;
            short8 wf[4];
            #pragma unroll
            for (int n = 0; n < 4; n++) wf[n] = *(const short8*)(wp[n] + ko);
            short8 af0 = cvt8v(x0, y0);
            short8 af1 = cvt8v(x1, y1);
            if (s < 15) {                        // prefetch next step's A (HBM)
                x0 = *(const floatx4*)(a0 + ko + 32);
                y0 = *(const floatx4*)(a0 + ko + 36);
                x1 = *(const floatx4*)(a1 + ko + 32);
                y1 = *(const floatx4*)(a1 + ko + 36);
            }
            #pragma unroll
            for (int n = 0; n < 4; n++) {
                acc[0][n] = __builtin_amdgcn_mfma_f32_16x16x32_bf16(af0, wf[n], acc[0][n], 0, 0, 0);
                acc[1][n] = __builtin_amdgcn_mfma_f32_16x16x32_bf16(af1, wf[n], acc[1][n], 0, 0, 0);
            }
        }

        #pragma unroll
        for (int n = 0; n < 4; n++) {
            const int col = w * 64 + n * 16 + rA;
            const float bv = bias[col];
            #pragma unroll
            for (int m = 0; m < 2; m++) {
                #pragma unroll
                for (int i = 0; i < 4; i++) {
                    float val = acc[m][n][i] + bv;
                    val = fmaxf(val, 0.f);
                    Pl[m * 16 + q * 4 + i][col] = f2bfbits(val);
                }
            }
        }
    }
    __syncthreads();

    // ---- Phase 2: attention ----
    // Preload A-frags from LDS (one-time); reused across all active n-steps.
    short8 af[2][8];
    #pragma unroll
    for (int t = 0; t < 2; t++)
        #pragma unroll
        for (int s = 0; s < 8; s++)
            af[t][s] = *(const short8*)&Pl[t * 16 + rA][s * 32 + q * 8];

    half2v acc[2][16][2];                // exp values, f16-packed (RTNE)
    #pragma unroll
    for (int t = 0; t < 2; t++)
        #pragma unroll
        for (int ns = 0; ns < 16; ns++) {
            acc[t][ns][0] = (half2v){(_Float16)0.f, (_Float16)0.f};
            acc[t][ns][1] = (half2v){(_Float16)0.f, (_Float16)0.f};
        }
    float psum[2][4];
    #pragma unroll
    for (int t = 0; t < 2; t++)
        #pragma unroll
        for (int i = 0; i < 4; i++) psum[t][i] = 0.f;

    // E rows for this wave's INTERLEAVED steps: row = ns*64 + w*16 + rA
    const ushort_t* erow = E + (long)(b * NEN + w * 16 + rA) * EF + q * 8;

    short8 bf[2][8];
    if (w * 16 < ne) {                   // prologue: load step 0
        #pragma unroll
        for (int s = 0; s < 8; s++) bf[0][s] = *(const short8*)(erow + s * 32);
    }

    #pragma unroll
    for (int ns = 0; ns < 16; ns++) {
        const int col0 = ns * 64 + w * 16;
        if (col0 < ne) {                 // wave-uniform skip, balanced across waves
            const int cur = ns & 1;      // compile-time under full unroll
            if (ns < 15) {               // prefetch step ns+1's E (garbage-safe)
                const ushort_t* epn = erow + (long)(ns + 1) * 64 * EF;
                #pragma unroll
                for (int s = 0; s < 8; s++) bf[cur ^ 1][s] = *(const short8*)(epn + s * 32);
            }
            floatx4 c0 = (floatx4){0.f, 0.f, 0.f, 0.f};
            floatx4 c1 = (floatx4){0.f, 0.f, 0.f, 0.f};
            #pragma unroll
            for (int s = 0; s < 8; s++) {
                c0 = __builtin_amdgcn_mfma_f32_16x16x32_bf16(af[0][s], bf[cur][s], c0, 0, 0, 0);
                c1 = __builtin_amdgcn_mfma_f32_16x16x32_bf16(af[1][s], bf[cur][s], c1, 0, 0, 0);
            }
            const int col = col0 + rA;
            const bool on = col < ne;    // boundary lanes: garbage E rows masked off
            #pragma unroll
            for (int i = 0; i < 4; i++) {
                float e0 = on ? __expf(c0[i] * 0.0625f) : 0.f;
                float e1 = on ? __expf(c1[i] * 0.0625f) : 0.f;
                psum[0][i] += e0; psum[1][i] += e1;
                c0[i] = e0; c1[i] = e1;
            }
            acc[0][ns][0] = (half2v){(_Float16)c0[0], (_Float16)c0[1]};
            acc[0][ns][1] = (half2v){(_Float16)c0[2], (_Float16)c0[3]};
            acc[1][ns][0] = (half2v){(_Float16)c1[0], (_Float16)c1[1]};
            acc[1][ns][1] = (half2v){(_Float16)c1[2], (_Float16)c1[3]};
        }
    }

    // Row sums: reduce over the 16 lanes sharing q (cols), then across waves via LDS.
    #pragma unroll
    for (int t = 0; t < 2; t++)
        #pragma unroll
        for (int i = 0; i < 4; i++) {
            float s = psum[t][i];
            s += __shfl_xor(s, 1);
            s += __shfl_xor(s, 2);
            s += __shfl_xor(s, 4);
            s += __shfl_xor(s, 8);
            psum[t][i] = s;
        }
    if (rA == 0) {
        #pragma unroll
        for (int t = 0; t < 2; t++)
            #pragma unroll
            for (int i = 0; i < 4; i++)
                lsum[w][t * 16 + q * 4 + i] = psum[t][i];
    }
    __syncthreads();

    float inv[2][4];
    #pragma unroll
    for (int t = 0; t < 2; t++)
        #pragma unroll
        for (int i = 0; i < 4; i++) {
            const int r = t * 16 + q * 4 + i;
            const float tot = lsum[0][r] + lsum[1][r] + lsum[2][r] + lsum[3][r];
            inv[t][i] = (ne > 0) ? (1.f / tot) : 0.f;
        }

    const float uni = 1.f / 1024.f;
    // out is never re-read: nontemporal stores keep the 268MB stream out of L2.
    float* orow = out + ((long)(b * NU + ut * 32)) * (long)NEN + w * 16;
    #pragma unroll
    for (int ns = 0; ns < 16; ns++) {
        #pragma unroll
        for (int t = 0; t < 2; t++) {
            #pragma unroll
            for (int i = 0; i < 4; i++) {
                const int u = t * 16 + q * 4 + i;
                const float num = (float)acc[t][ns][i >> 1][i & 1];
                const float val = (ne == 0) ? uni : num * inv[t][i];
                __builtin_nontemporal_store(val, &orow[(long)u * NEN + ns * 64 + rA]);
            }
        }
    }
}

extern "C" void kernel_launch(void* const* d_in, const int* in_sizes, int n_in,
                              void* d_out, int out_size, void* d_ws, size_t ws_size,
                              hipStream_t stream) {
    (void)in_sizes; (void)n_in; (void)out_size; (void)ws_size;
    const float* ufeat = (const float*)d_in[0];
    const float* efeat = (const float*)d_in[1];
    const int*   nen   = (const int*)d_in[2];
    const float* v     = (const float*)d_in[3];
    const float* g     = (const float*)d_in[4];
    const float* bias  = (const float*)d_in[5];
    float* out = (float*)d_out;

    float*    ws0 = (float*)d_ws;
    ushort_t* wsW = (ushort_t*)((char*)d_ws + 1024);        // 256 KB
    ushort_t* wsE = (ushort_t*)((char*)d_ws + (1u << 20));  // 32 MB

    hipMemsetAsync(d_ws, 0, 256, stream);
    knorm<<<256, 256, 0, stream>>>(v, ws0);
    kconv<<<16512, 256, 0, stream>>>(v, g, efeat, ws0, nen, wsW, wsE);
    kfused<<<2048, 256, 0, stream>>>(ufeat, wsW, bias, wsE, nen, out);
}